// Round 1
// baseline (571.190 us; speedup 1.0000x reference)
//
#include <hip/hip_runtime.h>
#include <hip/hip_bf16.h>
#include <math.h>

#define Bb 64
#define Nn 128
#define FNf 64
#define Ss 1033
#define EMBe 50

typedef float f4 __attribute__((ext_vector_type(4)));

// ---- workspace offsets (in floats) ----
constexpr size_t OFF_H     = 0;                         // 2 * 524288  (h per graph)
constexpr size_t OFF_HW    = OFF_H     + 2*524288;      // 2 * 524288  (h @ W_msg)
constexpr size_t OFF_EMSG  = OFF_HW    + 2*524288;      // 2 * 524288  (edge_msg)
constexpr size_t OFF_MASK  = OFF_EMSG  + 2*524288;      // 2 * 8192    (node mask float)
constexpr size_t OFF_OUT12 = OFF_MASK  + 2*8192;        // 2 * 8192    (graph readouts)
constexpr size_t OFF_PPRE  = OFF_OUT12 + 2*8192;        // 2 * 16384   (dec1 pre-act accum)
constexpr size_t OFF_PBN   = OFF_PPRE  + 2*16384;       // 2 * 16384   (post-BN)
constexpr size_t OFF_XW    = OFF_PBN   + 2*16384;       // 2 * 2115584 (x@W_ih.T + biases)
constexpr size_t OFF_HS    = OFF_XW    + 2*2115584;     // 2 * 528896  (LSTM hidden seq)
constexpr size_t OFF_W2F   = OFF_HS    + 2*528896;      // 2 * 256
constexpr size_t OFF_WMF   = OFF_W2F   + 2*256;         // 2 * 200
constexpr size_t OFF_WSF   = OFF_WMF   + 2*200;         // 963
constexpr size_t OFF_CONST = OFF_WSF   + 964;           // 4
constexpr size_t OFF_COUNT = OFF_CONST + 4;             // 2 * 8192 (int)
constexpr size_t OFF_NZ    = OFF_COUNT + 2*8192;        // 2 * 524288 (int)
constexpr size_t OFF_AVAL  = OFF_NZ    + 2*524288;      // 2 * 524288

__device__ inline f4 relu4(f4 v) {
  v[0] = fmaxf(v[0], 0.f); v[1] = fmaxf(v[1], 0.f);
  v[2] = fmaxf(v[2], 0.f); v[3] = fmaxf(v[3], 0.f);
  return v;
}

// ---------------- K1: adjacency compaction + edge_msg + h init -------------
// grid (8192, 2), block 64 (one wave per (b,n) row)
__global__ __launch_bounds__(64) void k1_prep(
    const float* __restrict__ adj1, const float* __restrict__ adj2,
    const float* __restrict__ edges1, const float* __restrict__ edges2,
    const float* __restrict__ nodes1, const float* __restrict__ nodes2,
    const float* __restrict__ We1, const float* __restrict__ We2,
    float* __restrict__ ws) {
  int row = blockIdx.x;
  int g = blockIdx.y;
  int t = threadIdx.x;
  const float* adj   = g ? adj2 : adj1;
  const float* edges = g ? edges2 : edges1;
  const float* nodes = g ? nodes2 : nodes1;
  const float* We    = g ? We2 : We1;
  float* h     = ws + OFF_H    + (size_t)g * 524288;
  float* emsg  = ws + OFF_EMSG + (size_t)g * 524288;
  float* maskf = ws + OFF_MASK + (size_t)g * 8192;
  int*   cntg  = (int*)(ws + OFF_COUNT) + (size_t)g * 8192;
  int*   nz    = (int*)(ws + OFF_NZ)    + (size_t)g * 524288;
  float* aval  = ws + OFF_AVAL + (size_t)g * 524288;

  __shared__ int   lidx[64];
  __shared__ float lav[64];
  __shared__ float les[16];

  const float* arow = adj + (size_t)row * 128;
  float a0 = arow[t], a1 = arow[64 + t];
  unsigned long long m0 = __ballot(a0 != 0.f);
  unsigned long long m1 = __ballot(a1 != 0.f);
  int c0 = __popcll(m0);
  int cnt = c0 + __popcll(m1);
  unsigned long long below = ((unsigned long long)1 << t) - 1ull;
  if (a0 != 0.f) { int pos = __popcll(m0 & below); if (pos < 64) { lidx[pos] = t; lav[pos] = a0; } }
  if (a1 != 0.f) { int pos = c0 + __popcll(m1 & below); if (pos < 64) { lidx[pos] = t + 64; lav[pos] = a1; } }
  int cc = cnt > 64 ? 64 : cnt;
  __syncthreads();

  // persist compact lists
  if (t < cc) { nz[(size_t)row * 64 + t] = lidx[t]; aval[(size_t)row * 64 + t] = lav[t]; }
  // init h = nodes
  h[(size_t)row * 64 + t] = nodes[(size_t)row * 64 + t];

  // es[f] = sum_nz a * edges[row, m, f]
  int f = t & 15, js = t >> 4;
  float es = 0.f;
  const float* erow = edges + (size_t)row * 128 * 16;
  for (int j = js; j < cc; j += 4) es += lav[j] * erow[lidx[j] * 16 + f];
  es += __shfl_xor(es, 16);
  es += __shfl_xor(es, 32);
  if (t < 16) les[t] = es;
  __syncthreads();

  // edge_msg[k] = sum_f es[f] * W_edge[f,k]
  float acc = 0.f;
  #pragma unroll
  for (int ff = 0; ff < 16; ++ff) acc += les[ff] * We[ff * 64 + t];
  emsg[(size_t)row * 64 + t] = acc;
  if (t == 0) { maskf[row] = cnt > 0 ? 1.f : 0.f; cntg[row] = cc; }
}

// ---------------- K_hW: hW = h @ W_msg ------------------------------------
// grid (512, 2), block 256 (16 rows per block)
__global__ __launch_bounds__(256) void k_hw(
    const float* __restrict__ Wm1, const float* __restrict__ Wm2,
    float* __restrict__ ws) {
  int g = blockIdx.y;
  const float* Wm = g ? Wm2 : Wm1;
  const float* h = ws + OFF_H + (size_t)g * 524288;
  float* hW = ws + OFF_HW + (size_t)g * 524288;
  __shared__ __attribute__((aligned(16))) float wlds[64 * 64];
  __shared__ __attribute__((aligned(16))) float hlds[16 * 64];
  int t = threadIdx.x;
  for (int i = t; i < 4096; i += 256) wlds[i] = Wm[i];
  int base = blockIdx.x * 16;
  for (int i = t; i < 1024; i += 256) hlds[i] = h[(size_t)base * 64 + i];
  __syncthreads();
  int k4 = (t & 15) * 4, rg = t >> 4;
  f4 acc = {0.f, 0.f, 0.f, 0.f};
  #pragma unroll 8
  for (int f = 0; f < 64; ++f) {
    float hv = hlds[rg * 64 + f];
    f4 w = *(const f4*)&wlds[f * 64 + k4];
    acc += hv * w;
  }
  *(f4*)&hW[(size_t)(base + rg) * 64 + k4] = acc;
}

// ---------------- K_msgupd: msg gather + update + relu + mask --------------
// grid (512, 2), block 256
__global__ __launch_bounds__(256) void k_msgupd(
    const float* __restrict__ Wup1, const float* __restrict__ Wup2,
    const float* __restrict__ bup1, const float* __restrict__ bup2,
    float* __restrict__ ws) {
  int g = blockIdx.y;
  const float* Wup = g ? Wup2 : Wup1;
  const float* bup = g ? bup2 : bup1;
  float* h = ws + OFF_H + (size_t)g * 524288;
  const float* hW = ws + OFF_HW + (size_t)g * 524288;
  const float* emsg = ws + OFF_EMSG + (size_t)g * 524288;
  const int* cntg = (const int*)(ws + OFF_COUNT) + (size_t)g * 8192;
  const int* nz = (const int*)(ws + OFF_NZ) + (size_t)g * 524288;
  const float* aval = ws + OFF_AVAL + (size_t)g * 524288;
  __shared__ __attribute__((aligned(16))) float wlds[128 * 64];
  __shared__ __attribute__((aligned(16))) float mlds[16 * 64];
  __shared__ __attribute__((aligned(16))) float hlds[16 * 64];
  int t = threadIdx.x;
  for (int i = t; i < 8192; i += 256) wlds[i] = Wup[i];
  int base = blockIdx.x * 16;
  int k4 = (t & 15) * 4, rg = t >> 4;
  int row = base + rg;
  int b = base >> 7;
  int cnt = cntg[row];
  f4 acc = *(const f4*)&emsg[(size_t)row * 64 + k4];
  const int* nzr = nz + (size_t)row * 64;
  const float* avr = aval + (size_t)row * 64;
  const float* hWb = hW + (size_t)b * 128 * 64;
  for (int j = 0; j < cnt; ++j) {
    int m = nzr[j];
    float av = avr[j];
    acc += av * *(const f4*)&hWb[m * 64 + k4];
  }
  *(f4*)&mlds[rg * 64 + k4] = acc;
  *(f4*)&hlds[rg * 64 + k4] = *(const f4*)&h[(size_t)row * 64 + k4];
  __syncthreads();
  f4 u = *(const f4*)&bup[k4];
  #pragma unroll 8
  for (int f = 0; f < 64; ++f) u += hlds[rg * 64 + f] * *(const f4*)&wlds[f * 64 + k4];
  #pragma unroll 8
  for (int f = 0; f < 64; ++f) u += mlds[rg * 64 + f] * *(const f4*)&wlds[(64 + f) * 64 + k4];
  u = relu4(u);
  if (cnt > 0) *(f4*)&h[(size_t)row * 64 + k4] = u;
}

// ---------------- K_read: readout r = relu([h,nodes]@W_read+b), masked sum -
// grid (512, 2 ktiles, 2 graphs), block 256
__global__ __launch_bounds__(256) void k_read(
    const float* __restrict__ Wr1, const float* __restrict__ Wr2,
    const float* __restrict__ br1, const float* __restrict__ br2,
    const float* __restrict__ nodes1, const float* __restrict__ nodes2,
    float* __restrict__ ws) {
  int g = blockIdx.z, kt = blockIdx.y;
  const float* Wr = g ? Wr2 : Wr1;
  const float* br = g ? br2 : br1;
  const float* nodes = g ? nodes2 : nodes1;
  const float* h = ws + OFF_H + (size_t)g * 524288;
  const float* maskf = ws + OFF_MASK + (size_t)g * 8192;
  float* out12 = ws + OFF_OUT12 + (size_t)g * 8192;
  __shared__ __attribute__((aligned(16))) float wlds[128 * 64];
  __shared__ __attribute__((aligned(16))) float hlds[16 * 64];
  __shared__ __attribute__((aligned(16))) float nlds[16 * 64];
  __shared__ __attribute__((aligned(16))) float red[16 * 64];
  int t = threadIdx.x;
  for (int i = t; i < 8192; i += 256) {
    int f = i >> 6, kk = i & 63;
    wlds[i] = Wr[f * 128 + kt * 64 + kk];
  }
  int base = blockIdx.x * 16;
  for (int i = t; i < 1024; i += 256) {
    hlds[i] = h[(size_t)base * 64 + i];
    nlds[i] = nodes[(size_t)base * 64 + i];
  }
  __syncthreads();
  int k4 = (t & 15) * 4, rg = t >> 4, row = base + rg, b = base >> 7;
  f4 acc = *(const f4*)&br[kt * 64 + k4];
  #pragma unroll 8
  for (int f = 0; f < 64; ++f) acc += hlds[rg * 64 + f] * *(const f4*)&wlds[f * 64 + k4];
  #pragma unroll 8
  for (int f = 0; f < 64; ++f) acc += nlds[rg * 64 + f] * *(const f4*)&wlds[(64 + f) * 64 + k4];
  acc = relu4(acc);
  float mf = maskf[row];
  acc *= mf;
  *(f4*)&red[rg * 64 + k4] = acc;
  __syncthreads();
  for (int off = 8; off; off >>= 1) {
    if (rg < off) {
      f4 v = *(f4*)&red[rg * 64 + k4] + *(f4*)&red[(rg + off) * 64 + k4];
      *(f4*)&red[rg * 64 + k4] = v;
    }
    __syncthreads();
  }
  if (rg == 0) {
    float* dst = out12 + (size_t)b * 128 + kt * 64 + k4;
    f4 v = *(f4*)&red[k4];
    atomicAdd(dst + 0, v[0]); atomicAdd(dst + 1, v[1]);
    atomicAdd(dst + 2, v[2]); atomicAdd(dst + 3, v[3]);
  }
}

// ---------------- K6: embedding + LayerNorm + x@W_ih.T + biases ------------
// grid (2066, 2), block 256 (8 groups x 32 lanes, 4 tokens per group)
__global__ __launch_bounds__(256) void k6_xw(
    const int* __restrict__ ids1, const int* __restrict__ ids2,
    const float* __restrict__ we, const float* __restrict__ pe,
    const float* __restrict__ lng, const float* __restrict__ lnb,
    const float* __restrict__ Wih, const float* __restrict__ bih,
    const float* __restrict__ bhh, float* __restrict__ ws) {
  int p = blockIdx.y;
  const int* ids = p ? ids2 : ids1;
  float* xw = ws + OFF_XW + (size_t)p * 2115584;
  __shared__ float wlds[1600];
  __shared__ float glds[50], blds[50], bs[32];
  __shared__ float xl[8][52];
  int t = threadIdx.x;
  for (int i = t; i < 1600; i += 256) wlds[i] = Wih[i];
  if (t < 50) { glds[t] = lng[t]; blds[t] = lnb[t]; }
  if (t < 32) bs[t] = bih[t] + bhh[t];
  __syncthreads();
  int grp = t >> 5, tl = t & 31;
  int q0 = blockIdx.x * 32 + grp * 4;
  for (int qq = 0; qq < 4; ++qq) {
    int q = q0 + qq;                  // q = b*S + s, total exactly 64*1033
    int s = q % Ss;
    int id = ids[q];
    const float* wr = we + (size_t)id * 50;
    const float* pr = pe + (size_t)s * 50;
    float x1 = wr[tl] + pr[tl];
    bool has2 = (tl + 32) < 50;
    float x2 = has2 ? (wr[tl + 32] + pr[tl + 32]) : 0.f;
    float sm = x1 + x2, sq = x1 * x1 + x2 * x2;
    #pragma unroll
    for (int off = 16; off; off >>= 1) {
      sm += __shfl_xor(sm, off, 32);
      sq += __shfl_xor(sq, off, 32);
    }
    float u = sm * (1.f / 50.f);
    float var = fmaxf(sq * (1.f / 50.f) - u * u, 0.f);
    float rstd = rsqrtf(var + 1e-12f);
    xl[grp][tl] = glds[tl] * (x1 - u) * rstd + blds[tl];
    if (has2) xl[grp][tl + 32] = glds[tl + 32] * (x2 - u) * rstd + blds[tl + 32];
    __syncthreads();
    float acc = bs[tl];
    #pragma unroll 10
    for (int k = 0; k < 50; ++k) acc += xl[grp][k] * wlds[tl * 50 + k];
    xw[(size_t)q * 32 + tl] = acc;
    __syncthreads();
  }
}

// ---------------- K7: sequential LSTM scan ---------------------------------
// grid (8, 2), block 256 (32 lanes per batch element)
__global__ __launch_bounds__(256) void k7_lstm(
    const float* __restrict__ Whh, float* __restrict__ ws) {
  int p = blockIdx.y;
  const float* xw = ws + OFF_XW + (size_t)p * 2115584;
  float* hs = ws + OFF_HS + (size_t)p * 528896;
  int lane = threadIdx.x & 31;
  int b = blockIdx.x * 8 + (threadIdx.x >> 5);
  const float* xwp = xw + (size_t)b * Ss * 32 + lane;
  float* hsp = hs + (size_t)b * Ss * 8;
  float w[8];
  #pragma unroll
  for (int f = 0; f < 8; ++f) w[f] = Whh[lane * 8 + f];
  bool isg = (lane >> 3) == 2;
  float sgn = isg ? -2.f : -1.f;
  float mulv = isg ? 2.f : 1.f;
  float addv = isg ? -1.f : 0.f;
  float h[8] = {0.f, 0.f, 0.f, 0.f, 0.f, 0.f, 0.f, 0.f};
  float c = 0.f;
  int k = lane & 7;
  float g_next = xwp[0];
  for (int s = 0; s < Ss; ++s) {
    float g0 = g_next;
    if (s + 1 < Ss) g_next = xwp[(size_t)(s + 1) * 32];  // prefetch ahead of chain
    #pragma unroll
    for (int f = 0; f < 8; ++f) g0 = fmaf(h[f], w[f], g0);
    float e = __expf(g0 * sgn);
    float r = __builtin_amdgcn_rcpf(1.f + e);
    float a = fmaf(r, mulv, addv);         // sigmoid or tanh per lane group
    float ai = __shfl(a, k, 32);
    float af = __shfl(a, 8 + k, 32);
    float ag = __shfl(a, 16 + k, 32);
    float ao = __shfl(a, 24 + k, 32);
    c = fmaf(af, c, ai * ag);
    float e2 = __expf(-2.f * c);
    float th = fmaf(__builtin_amdgcn_rcpf(1.f + e2), 2.f, -1.f);
    float ho = ao * th;
    if (lane < 8) hsp[(size_t)s * 8 + lane] = ho;
    #pragma unroll
    for (int f = 0; f < 8; ++f) h[f] = __shfl(ho, f, 32);
  }
}

// ---------------- K8: dec_W1 GEMM (split-K, atomic accumulate) -------------
// grid (32 kchunks, 4 jtiles, 2 proteins), block 256
__global__ __launch_bounds__(256) void k8_dec(
    const float* __restrict__ W1, float* __restrict__ ws) {
  int ks = blockIdx.x, jt = blockIdx.y, p = blockIdx.z;
  const float* hs = ws + OFF_HS + (size_t)p * 528896;
  float* pp = ws + OFF_PPRE + (size_t)p * 16384;
  int s0 = ks * 33;
  int s1 = s0 + 33; if (s1 > Ss) s1 = Ss;
  int j0 = jt * 64;
  __shared__ __attribute__((aligned(16))) float hsl[512];
  __shared__ __attribute__((aligned(16))) float w1l[512];
  int t = threadIdx.x;
  int jl = (t & 15) * 4, bb = (t >> 4) * 4;
  f4 acc[4] = {};
  for (int s = s0; s < s1; ++s) {
    int i2 = 2 * t;
    hsl[i2]     = hs[((size_t)(i2 >> 3) * Ss + s) * 8 + (i2 & 7)];
    hsl[i2 + 1] = hs[((size_t)((i2 + 1) >> 3) * Ss + s) * 8 + ((i2 + 1) & 7)];
    w1l[t]       = W1[(size_t)(s * 8 + (t >> 6)) * 256 + j0 + (t & 63)];
    w1l[t + 256] = W1[(size_t)(s * 8 + ((t + 256) >> 6)) * 256 + j0 + ((t + 256) & 63)];
    __syncthreads();
    #pragma unroll
    for (int l = 0; l < 8; ++l) {
      f4 wv = *(const f4*)&w1l[l * 64 + jl];
      #pragma unroll
      for (int i = 0; i < 4; ++i) acc[i] += hsl[(bb + i) * 8 + l] * wv;
    }
    __syncthreads();
  }
  for (int i = 0; i < 4; ++i) {
    float* dst = pp + (size_t)(bb + i) * 256 + j0 + jl;
    atomicAdd(dst + 0, acc[i][0]); atomicAdd(dst + 1, acc[i][1]);
    atomicAdd(dst + 2, acc[i][2]); atomicAdd(dst + 3, acc[i][3]);
  }
}

// ---------------- K9: bias + relu + BatchNorm (batch stats) ----------------
// grid (2,), block 256 (thread = feature j)
__global__ __launch_bounds__(256) void k9_bn(
    const float* __restrict__ b1, const float* __restrict__ bng,
    const float* __restrict__ bnb, float* __restrict__ ws) {
  int p = blockIdx.x, j = threadIdx.x;
  const float* pp = ws + OFF_PPRE + (size_t)p * 16384;
  float* pbn = ws + OFF_PBN + (size_t)p * 16384;
  float bj = b1[j];
  float sm = 0.f, sq = 0.f;
  for (int b = 0; b < 64; ++b) {
    float v = fmaxf(pp[b * 256 + j] + bj, 0.f);
    sm += v; sq += v * v;
  }
  float m = sm * (1.f / 64.f);
  float var = fmaxf(sq * (1.f / 64.f) - m * m, 0.f);
  float rstd = rsqrtf(var + 1e-5f);
  float sc = bng[j] * rstd, sh = bnb[j] - m * sc;
  for (int b = 0; b < 64; ++b) {
    float v = fmaxf(pp[b * 256 + j] + bj, 0.f);
    pbn[b * 256 + j] = sc * v + sh;
  }
}

// ---------------- K_pre: fold small matrices through W_final ---------------
// grid (1,), block 256
__global__ __launch_bounds__(256) void k_pre(
    const float* __restrict__ W2, const float* __restrict__ b2,
    const float* __restrict__ Wm, const float* __restrict__ bm,
    const float* __restrict__ Wsd, const float* __restrict__ bsd,
    const float* __restrict__ Wf, const float* __restrict__ bf,
    float* __restrict__ ws) {
  __shared__ float wf[468];
  int t = threadIdx.x;
  for (int i = t; i < 468; i += 256) wf[i] = Wf[i];
  __syncthreads();
  float* w2f = ws + OFF_W2F;
  float* wmf = ws + OFF_WMF;
  float* wsf = ws + OFF_WSF;
  float* cst = ws + OFF_CONST;
  {
    float a1 = 0.f, a2 = 0.f;
    for (int k = 0; k < 45; ++k) {
      float v = W2[t * 45 + k];
      a1 += v * wf[128 + k];
      a2 += v * wf[346 + k];
    }
    w2f[t] = a1; w2f[256 + t] = a2;
  }
  if (t < 200) {
    float a1 = 0.f, a2 = 0.f;
    for (int k = 0; k < 45; ++k) {
      float v = Wm[t * 45 + k];
      a1 += v * wf[173 + k];
      a2 += v * wf[391 + k];
    }
    wmf[t] = a1; wmf[200 + t] = a2;
  }
  for (int i = t; i < 963; i += 256) {
    float a = 0.f;
    for (int k = 0; k < 32; ++k) a += Wsd[i * 32 + k] * wf[436 + k];
    wsf[i] = a;
  }
  if (t == 0) {
    float cc = bf[0];
    for (int k = 0; k < 45; ++k)
      cc += b2[k] * (wf[128 + k] + wf[346 + k]) + bm[k] * (wf[173 + k] + wf[391 + k]);
    for (int k = 0; k < 32; ++k) cc += bsd[k] * wf[436 + k];
    cst[0] = cc;
  }
}

// ---------------- K_final: per-row big dot ----------------------------------
// grid (64,), block 256
__global__ __launch_bounds__(256) void k_final(
    const float* __restrict__ d1m, const float* __restrict__ d2m,
    const float* __restrict__ se, const float* __restrict__ Wf,
    float* __restrict__ ws, float* __restrict__ out) {
  int b = blockIdx.x, t = threadIdx.x;
  const float* out12 = ws + OFF_OUT12;
  const float* pbn = ws + OFF_PBN;
  const float* w2f = ws + OFF_W2F;
  const float* wmf = ws + OFF_WMF;
  const float* wsf = ws + OFF_WSF;
  float acc = 0.f;
  if (t < 128) {
    acc += out12[b * 128 + t] * Wf[t];
    acc += out12[8192 + b * 128 + t] * Wf[218 + t];
  }
  acc += pbn[b * 256 + t] * w2f[t];
  acc += pbn[16384 + b * 256 + t] * w2f[256 + t];
  if (t < 200) {
    acc += d1m[b * 200 + t] * wmf[t];
    acc += d2m[b * 200 + t] * wmf[200 + t];
  }
  for (int i = t; i < 963; i += 256) acc += se[b * 963 + i] * wsf[i];
  __shared__ float red[256];
  red[t] = acc;
  __syncthreads();
  for (int off = 128; off; off >>= 1) {
    if (t < off) red[t] += red[t + off];
    __syncthreads();
  }
  if (t == 0) out[b] = red[0] + (ws + OFF_CONST)[0];
}

extern "C" void kernel_launch(void* const* d_in, const int* in_sizes, int n_in,
                              void* d_out, int out_size, void* d_ws, size_t ws_size,
                              hipStream_t stream) {
  const float* adj1  = (const float*)d_in[0];
  const float* nodes1= (const float*)d_in[1];
  const float* edges1= (const float*)d_in[2];
  const float* adj2  = (const float*)d_in[3];
  const float* nodes2= (const float*)d_in[4];
  const float* edges2= (const float*)d_in[5];
  const float* d1m   = (const float*)d_in[6];
  const float* d2m   = (const float*)d_in[7];
  const int*   ids1  = (const int*)d_in[8];
  const int*   ids2  = (const int*)d_in[9];
  const float* se    = (const float*)d_in[10];
  const float* we    = (const float*)d_in[11];
  const float* pe    = (const float*)d_in[12];
  const float* lng   = (const float*)d_in[13];
  const float* lnb   = (const float*)d_in[14];
  const float* Wih   = (const float*)d_in[15];
  const float* Whh   = (const float*)d_in[16];
  const float* bih   = (const float*)d_in[17];
  const float* bhh   = (const float*)d_in[18];
  const float* W1    = (const float*)d_in[19];
  const float* b1    = (const float*)d_in[20];
  const float* bng   = (const float*)d_in[21];
  const float* bnb   = (const float*)d_in[22];
  const float* W2    = (const float*)d_in[23];
  const float* b2    = (const float*)d_in[24];
  const float* Wm1   = (const float*)d_in[25];
  const float* We1   = (const float*)d_in[26];
  const float* Wup1  = (const float*)d_in[27];
  const float* bup1  = (const float*)d_in[28];
  const float* Wr1   = (const float*)d_in[29];
  const float* br1   = (const float*)d_in[30];
  const float* Wm2   = (const float*)d_in[31];
  const float* We2   = (const float*)d_in[32];
  const float* Wup2  = (const float*)d_in[33];
  const float* bup2  = (const float*)d_in[34];
  const float* Wr2   = (const float*)d_in[35];
  const float* br2   = (const float*)d_in[36];
  const float* Wmo   = (const float*)d_in[37];
  const float* bmo   = (const float*)d_in[38];
  const float* Wsd   = (const float*)d_in[39];
  const float* bsd   = (const float*)d_in[40];
  const float* Wf    = (const float*)d_in[41];
  const float* bf    = (const float*)d_in[42];
  float* ws = (float*)d_ws;
  float* out = (float*)d_out;

  // zero accumulators (out12 + p_pre are contiguous)
  hipMemsetAsync(ws + OFF_OUT12, 0, (2 * 8192 + 2 * 16384) * sizeof(float), stream);

  // MPNN prep: neighbor lists, edge_msg, mask, h init
  k1_prep<<<dim3(8192, 2), 64, 0, stream>>>(adj1, adj2, edges1, edges2,
                                            nodes1, nodes2, We1, We2, ws);
  // T = 3 message-passing iterations
  for (int it = 0; it < 3; ++it) {
    k_hw<<<dim3(512, 2), 256, 0, stream>>>(Wm1, Wm2, ws);
    k_msgupd<<<dim3(512, 2), 256, 0, stream>>>(Wup1, Wup2, bup1, bup2, ws);
  }
  // readout
  k_read<<<dim3(512, 2, 2), 256, 0, stream>>>(Wr1, Wr2, br1, br2, nodes1, nodes2, ws);

  // protein branch
  k6_xw<<<dim3(2066, 2), 256, 0, stream>>>(ids1, ids2, we, pe, lng, lnb, Wih, bih, bhh, ws);
  k7_lstm<<<dim3(8, 2), 256, 0, stream>>>(Whh, ws);
  k8_dec<<<dim3(32, 4, 2), 256, 0, stream>>>(W1, ws);
  k9_bn<<<2, 256, 0, stream>>>(b1, bng, bnb, ws);

  // final assembly
  k_pre<<<1, 256, 0, stream>>>(W2, b2, Wmo, bmo, Wsd, bsd, Wf, bf, ws);
  k_final<<<64, 256, 0, stream>>>(d1m, d2m, se, Wf, ws, out);
}

// Round 2
// 553.413 us; speedup vs baseline: 1.0321x; 1.0321x over previous
//
#include <hip/hip_runtime.h>
#include <hip/hip_bf16.h>
#include <math.h>

#define Bb 64
#define Nn 128
#define FNf 64
#define Ss 1033
#define EMBe 50

typedef float f4 __attribute__((ext_vector_type(4)));
typedef float f2 __attribute__((ext_vector_type(2)));

// ---- workspace offsets (in floats) ----
constexpr size_t OFF_H     = 0;                         // 2 * 524288  (h per graph)
constexpr size_t OFF_HW    = OFF_H     + 2*524288;      // 2 * 524288  (h @ W_msg)
constexpr size_t OFF_EMSG  = OFF_HW    + 2*524288;      // 2 * 524288  (edge_msg)
constexpr size_t OFF_MASK  = OFF_EMSG  + 2*524288;      // 2 * 8192    (node mask float)
constexpr size_t OFF_OUT12 = OFF_MASK  + 2*8192;        // 2 * 8192    (graph readouts)
constexpr size_t OFF_PPRE  = OFF_OUT12 + 2*8192;        // 2 * 16384   (dec1 pre-act accum)
constexpr size_t OFF_PBN   = OFF_PPRE  + 2*16384;       // 2 * 16384   (post-BN)
constexpr size_t OFF_XW    = OFF_PBN   + 2*16384;       // 2 * 2115584 (x@W_ih.T + biases, permuted layout)
constexpr size_t OFF_HS    = OFF_XW    + 2*2115584;     // 2 * 528896  (LSTM hidden seq)
constexpr size_t OFF_W2F   = OFF_HS    + 2*528896;      // 2 * 256
constexpr size_t OFF_WMF   = OFF_W2F   + 2*256;         // 2 * 200
constexpr size_t OFF_WSF   = OFF_WMF   + 2*200;         // 963
constexpr size_t OFF_CONST = OFF_WSF   + 964;           // 4
constexpr size_t OFF_COUNT = OFF_CONST + 4;             // 2 * 8192 (int)
constexpr size_t OFF_NZ    = OFF_COUNT + 2*8192;        // 2 * 524288 (int)
constexpr size_t OFF_AVAL  = OFF_NZ    + 2*524288;      // 2 * 524288

__device__ inline f4 relu4(f4 v) {
  v[0] = fmaxf(v[0], 0.f); v[1] = fmaxf(v[1], 0.f);
  v[2] = fmaxf(v[2], 0.f); v[3] = fmaxf(v[3], 0.f);
  return v;
}

// DPP row rotate-right: dst[i] = src[(i - n) & 15] within each 16-lane row.
#define ROR16(x, n) __int_as_float(__builtin_amdgcn_update_dpp(0, __float_as_int(x), 0x120 + (n), 0xF, 0xF, true))

// ---------------- K1: adjacency compaction + edge_msg + h init -------------
// grid (8192, 2), block 64 (one wave per (b,n) row)
__global__ __launch_bounds__(64) void k1_prep(
    const float* __restrict__ adj1, const float* __restrict__ adj2,
    const float* __restrict__ edges1, const float* __restrict__ edges2,
    const float* __restrict__ nodes1, const float* __restrict__ nodes2,
    const float* __restrict__ We1, const float* __restrict__ We2,
    float* __restrict__ ws) {
  int row = blockIdx.x;
  int g = blockIdx.y;
  int t = threadIdx.x;
  const float* adj   = g ? adj2 : adj1;
  const float* edges = g ? edges2 : edges1;
  const float* nodes = g ? nodes2 : nodes1;
  const float* We    = g ? We2 : We1;
  float* h     = ws + OFF_H    + (size_t)g * 524288;
  float* emsg  = ws + OFF_EMSG + (size_t)g * 524288;
  float* maskf = ws + OFF_MASK + (size_t)g * 8192;
  int*   cntg  = (int*)(ws + OFF_COUNT) + (size_t)g * 8192;
  int*   nz    = (int*)(ws + OFF_NZ)    + (size_t)g * 524288;
  float* aval  = ws + OFF_AVAL + (size_t)g * 524288;

  __shared__ int   lidx[64];
  __shared__ float lav[64];
  __shared__ float les[16];

  const float* arow = adj + (size_t)row * 128;
  float a0 = arow[t], a1 = arow[64 + t];
  unsigned long long m0 = __ballot(a0 != 0.f);
  unsigned long long m1 = __ballot(a1 != 0.f);
  int c0 = __popcll(m0);
  int cnt = c0 + __popcll(m1);
  unsigned long long below = ((unsigned long long)1 << t) - 1ull;
  if (a0 != 0.f) { int pos = __popcll(m0 & below); if (pos < 64) { lidx[pos] = t; lav[pos] = a0; } }
  if (a1 != 0.f) { int pos = c0 + __popcll(m1 & below); if (pos < 64) { lidx[pos] = t + 64; lav[pos] = a1; } }
  int cc = cnt > 64 ? 64 : cnt;
  __syncthreads();

  // persist compact lists
  if (t < cc) { nz[(size_t)row * 64 + t] = lidx[t]; aval[(size_t)row * 64 + t] = lav[t]; }
  // init h = nodes
  h[(size_t)row * 64 + t] = nodes[(size_t)row * 64 + t];

  // es[f] = sum_nz a * edges[row, m, f]
  int f = t & 15, js = t >> 4;
  float es = 0.f;
  const float* erow = edges + (size_t)row * 128 * 16;
  for (int j = js; j < cc; j += 4) es += lav[j] * erow[lidx[j] * 16 + f];
  es += __shfl_xor(es, 16);
  es += __shfl_xor(es, 32);
  if (t < 16) les[t] = es;
  __syncthreads();

  // edge_msg[k] = sum_f es[f] * W_edge[f,k]
  float acc = 0.f;
  #pragma unroll
  for (int ff = 0; ff < 16; ++ff) acc += les[ff] * We[ff * 64 + t];
  emsg[(size_t)row * 64 + t] = acc;
  if (t == 0) { maskf[row] = cnt > 0 ? 1.f : 0.f; cntg[row] = cc; }
}

// ---------------- K_hW: hW = h @ W_msg ------------------------------------
// grid (512, 2), block 256 (16 rows per block)
__global__ __launch_bounds__(256) void k_hw(
    const float* __restrict__ Wm1, const float* __restrict__ Wm2,
    float* __restrict__ ws) {
  int g = blockIdx.y;
  const float* Wm = g ? Wm2 : Wm1;
  const float* h = ws + OFF_H + (size_t)g * 524288;
  float* hW = ws + OFF_HW + (size_t)g * 524288;
  __shared__ __attribute__((aligned(16))) float wlds[64 * 64];
  __shared__ __attribute__((aligned(16))) float hlds[16 * 64];
  int t = threadIdx.x;
  for (int i = t; i < 4096; i += 256) wlds[i] = Wm[i];
  int base = blockIdx.x * 16;
  for (int i = t; i < 1024; i += 256) hlds[i] = h[(size_t)base * 64 + i];
  __syncthreads();
  int k4 = (t & 15) * 4, rg = t >> 4;
  f4 acc = {0.f, 0.f, 0.f, 0.f};
  #pragma unroll 8
  for (int f = 0; f < 64; ++f) {
    float hv = hlds[rg * 64 + f];
    f4 w = *(const f4*)&wlds[f * 64 + k4];
    acc += hv * w;
  }
  *(f4*)&hW[(size_t)(base + rg) * 64 + k4] = acc;
}

// ---------------- K_msgupd: msg gather + update + relu + mask --------------
// grid (512, 2), block 256
__global__ __launch_bounds__(256) void k_msgupd(
    const float* __restrict__ Wup1, const float* __restrict__ Wup2,
    const float* __restrict__ bup1, const float* __restrict__ bup2,
    float* __restrict__ ws) {
  int g = blockIdx.y;
  const float* Wup = g ? Wup2 : Wup1;
  const float* bup = g ? bup2 : bup1;
  float* h = ws + OFF_H + (size_t)g * 524288;
  const float* hW = ws + OFF_HW + (size_t)g * 524288;
  const float* emsg = ws + OFF_EMSG + (size_t)g * 524288;
  const int* cntg = (const int*)(ws + OFF_COUNT) + (size_t)g * 8192;
  const int* nz = (const int*)(ws + OFF_NZ) + (size_t)g * 524288;
  const float* aval = ws + OFF_AVAL + (size_t)g * 524288;
  __shared__ __attribute__((aligned(16))) float wlds[128 * 64];
  __shared__ __attribute__((aligned(16))) float mlds[16 * 64];
  __shared__ __attribute__((aligned(16))) float hlds[16 * 64];
  int t = threadIdx.x;
  for (int i = t; i < 8192; i += 256) wlds[i] = Wup[i];
  int base = blockIdx.x * 16;
  int k4 = (t & 15) * 4, rg = t >> 4;
  int row = base + rg;
  int b = base >> 7;
  int cnt = cntg[row];
  f4 acc = *(const f4*)&emsg[(size_t)row * 64 + k4];
  const int* nzr = nz + (size_t)row * 64;
  const float* avr = aval + (size_t)row * 64;
  const float* hWb = hW + (size_t)b * 128 * 64;
  for (int j = 0; j < cnt; ++j) {
    int m = nzr[j];
    float av = avr[j];
    acc += av * *(const f4*)&hWb[m * 64 + k4];
  }
  *(f4*)&mlds[rg * 64 + k4] = acc;
  *(f4*)&hlds[rg * 64 + k4] = *(const f4*)&h[(size_t)row * 64 + k4];
  __syncthreads();
  f4 u = *(const f4*)&bup[k4];
  #pragma unroll 8
  for (int f = 0; f < 64; ++f) u += hlds[rg * 64 + f] * *(const f4*)&wlds[f * 64 + k4];
  #pragma unroll 8
  for (int f = 0; f < 64; ++f) u += mlds[rg * 64 + f] * *(const f4*)&wlds[(64 + f) * 64 + k4];
  u = relu4(u);
  if (cnt > 0) *(f4*)&h[(size_t)row * 64 + k4] = u;
}

// ---------------- K_read: readout r = relu([h,nodes]@W_read+b), masked sum -
// grid (512, 2 ktiles, 2 graphs), block 256
__global__ __launch_bounds__(256) void k_read(
    const float* __restrict__ Wr1, const float* __restrict__ Wr2,
    const float* __restrict__ br1, const float* __restrict__ br2,
    const float* __restrict__ nodes1, const float* __restrict__ nodes2,
    float* __restrict__ ws) {
  int g = blockIdx.z, kt = blockIdx.y;
  const float* Wr = g ? Wr2 : Wr1;
  const float* br = g ? br2 : br1;
  const float* nodes = g ? nodes2 : nodes1;
  const float* h = ws + OFF_H + (size_t)g * 524288;
  const float* maskf = ws + OFF_MASK + (size_t)g * 8192;
  float* out12 = ws + OFF_OUT12 + (size_t)g * 8192;
  __shared__ __attribute__((aligned(16))) float wlds[128 * 64];
  __shared__ __attribute__((aligned(16))) float hlds[16 * 64];
  __shared__ __attribute__((aligned(16))) float nlds[16 * 64];
  __shared__ __attribute__((aligned(16))) float red[16 * 64];
  int t = threadIdx.x;
  for (int i = t; i < 8192; i += 256) {
    int f = i >> 6, kk = i & 63;
    wlds[i] = Wr[f * 128 + kt * 64 + kk];
  }
  int base = blockIdx.x * 16;
  for (int i = t; i < 1024; i += 256) {
    hlds[i] = h[(size_t)base * 64 + i];
    nlds[i] = nodes[(size_t)base * 64 + i];
  }
  __syncthreads();
  int k4 = (t & 15) * 4, rg = t >> 4, row = base + rg, b = base >> 7;
  f4 acc = *(const f4*)&br[kt * 64 + k4];
  #pragma unroll 8
  for (int f = 0; f < 64; ++f) acc += hlds[rg * 64 + f] * *(const f4*)&wlds[f * 64 + k4];
  #pragma unroll 8
  for (int f = 0; f < 64; ++f) acc += nlds[rg * 64 + f] * *(const f4*)&wlds[(64 + f) * 64 + k4];
  acc = relu4(acc);
  float mf = maskf[row];
  acc *= mf;
  *(f4*)&red[rg * 64 + k4] = acc;
  __syncthreads();
  for (int off = 8; off; off >>= 1) {
    if (rg < off) {
      f4 v = *(f4*)&red[rg * 64 + k4] + *(f4*)&red[(rg + off) * 64 + k4];
      *(f4*)&red[rg * 64 + k4] = v;
    }
    __syncthreads();
  }
  if (rg == 0) {
    float* dst = out12 + (size_t)b * 128 + kt * 64 + k4;
    f4 v = *(f4*)&red[k4];
    atomicAdd(dst + 0, v[0]); atomicAdd(dst + 1, v[1]);
    atomicAdd(dst + 2, v[2]); atomicAdd(dst + 3, v[3]);
  }
}

// ---------------- K6: embedding + LayerNorm + x@W_ih.T + biases ------------
// grid (2066, 2), block 256 (8 groups x 32 lanes, 4 tokens per group)
// Output layout permuted for k7's 16-lane DPP scheme:
//   orig gate index tl (0-7 i, 8-15 f, 16-23 g, 24-31 o), k = tl&7
//   lane L=k   (half0) holds float2 (i_k, g_k) at positions (2k, 2k+1)
//   lane L=8+k (half1) holds float2 (f_k, o_k) at positions (16+2k, 16+2k+1)
//   => newpos = tl<16 ? 2*tl : 2*tl-31
__global__ __launch_bounds__(256) void k6_xw(
    const int* __restrict__ ids1, const int* __restrict__ ids2,
    const float* __restrict__ we, const float* __restrict__ pe,
    const float* __restrict__ lng, const float* __restrict__ lnb,
    const float* __restrict__ Wih, const float* __restrict__ bih,
    const float* __restrict__ bhh, float* __restrict__ ws) {
  int p = blockIdx.y;
  const int* ids = p ? ids2 : ids1;
  float* xw = ws + OFF_XW + (size_t)p * 2115584;
  __shared__ float wlds[1600];
  __shared__ float glds[50], blds[50], bs[32];
  __shared__ float xl[8][52];
  int t = threadIdx.x;
  for (int i = t; i < 1600; i += 256) wlds[i] = Wih[i];
  if (t < 50) { glds[t] = lng[t]; blds[t] = lnb[t]; }
  if (t < 32) bs[t] = bih[t] + bhh[t];
  __syncthreads();
  int grp = t >> 5, tl = t & 31;
  int newpos = (tl < 16) ? 2 * tl : 2 * tl - 31;
  int q0 = blockIdx.x * 32 + grp * 4;
  for (int qq = 0; qq < 4; ++qq) {
    int q = q0 + qq;                  // q = b*S + s, total exactly 64*1033
    int s = q % Ss;
    int id = ids[q];
    const float* wr = we + (size_t)id * 50;
    const float* pr = pe + (size_t)s * 50;
    float x1 = wr[tl] + pr[tl];
    bool has2 = (tl + 32) < 50;
    float x2 = has2 ? (wr[tl + 32] + pr[tl + 32]) : 0.f;
    float sm = x1 + x2, sq = x1 * x1 + x2 * x2;
    #pragma unroll
    for (int off = 16; off; off >>= 1) {
      sm += __shfl_xor(sm, off, 32);
      sq += __shfl_xor(sq, off, 32);
    }
    float u = sm * (1.f / 50.f);
    float var = fmaxf(sq * (1.f / 50.f) - u * u, 0.f);
    float rstd = rsqrtf(var + 1e-12f);
    xl[grp][tl] = glds[tl] * (x1 - u) * rstd + blds[tl];
    if (has2) xl[grp][tl + 32] = glds[tl + 32] * (x2 - u) * rstd + blds[tl + 32];
    __syncthreads();
    float acc = bs[tl];
    #pragma unroll 10
    for (int k = 0; k < 50; ++k) acc += xl[grp][k] * wlds[tl * 50 + k];
    xw[(size_t)q * 32 + newpos] = acc;
    __syncthreads();
  }
}

// ---------------- K7: sequential LSTM scan (DPP, 16 lanes/batch) -----------
// grid (4, 2), block 256: 16 batches/block, 16 lanes per batch.
// lane = (half, k): half0 computes gates (i_k, g_k); half1 computes (f_k, o_k).
// hidden state ho_k duplicated at lanes k and 8+k; all cross-lane via DPP.
__global__ __launch_bounds__(256) void k7_lstm(
    const float* __restrict__ Whh, float* __restrict__ ws) {
  int p = blockIdx.y;
  const float* xw = ws + OFF_XW + (size_t)p * 2115584;
  float* hs = ws + OFF_HS + (size_t)p * 528896;
  int t = threadIdx.x;
  int lane16 = t & 15;
  int k = lane16 & 7;
  int half = lane16 >> 3;
  int b = blockIdx.x * 16 + (t >> 4);
  const float* xwp = xw + (size_t)b * Ss * 32 + lane16 * 2;
  float* hsp = hs + (size_t)b * Ss * 8 + k;
  int ga = half ? 8 + k : k;          // f_k or i_k  (sigmoid)
  int gb = half ? 24 + k : 16 + k;    // o_k or g_k  (sigmoid / tanh)
  // weights pre-rotated to match ROR16 delivery order: rotation r brings h_{(k-r)&7}
  float wa[8], wb[8];
  #pragma unroll
  for (int r = 0; r < 8; ++r) {
    int j = (k - r) & 7;
    wa[r] = Whh[ga * 8 + j];
    wb[r] = Whh[gb * 8 + j];
  }
  float sclb = half ? -1.f : -2.f;    // exp arg scale: sigmoid vs tanh
  float mulb = half ? 1.f : 2.f;
  float addb = half ? 0.f : -1.f;
  float ho = 0.f, c = 0.f;
  f2 x0 = *(const f2*)xwp;
  f2 x1 = *(const f2*)(xwp + 32);
  for (int s = 0; s < Ss; ++s) {
    f2 x2 = *(const f2*)(xwp + (size_t)(s + 2) * 32);  // prefetch distance 2 (stays inside ws)
    float acc_a = fmaf(ho, wa[0], x0.x);
    float acc_b = fmaf(ho, wb[0], x0.y);
    float h1 = ROR16(ho, 1); acc_a = fmaf(h1, wa[1], acc_a); acc_b = fmaf(h1, wb[1], acc_b);
    float h2 = ROR16(ho, 2); acc_a = fmaf(h2, wa[2], acc_a); acc_b = fmaf(h2, wb[2], acc_b);
    float h3 = ROR16(ho, 3); acc_a = fmaf(h3, wa[3], acc_a); acc_b = fmaf(h3, wb[3], acc_b);
    float h4 = ROR16(ho, 4); acc_a = fmaf(h4, wa[4], acc_a); acc_b = fmaf(h4, wb[4], acc_b);
    float h5 = ROR16(ho, 5); acc_a = fmaf(h5, wa[5], acc_a); acc_b = fmaf(h5, wb[5], acc_b);
    float h6 = ROR16(ho, 6); acc_a = fmaf(h6, wa[6], acc_a); acc_b = fmaf(h6, wb[6], acc_b);
    float h7 = ROR16(ho, 7); acc_a = fmaf(h7, wa[7], acc_a); acc_b = fmaf(h7, wb[7], acc_b);
    // activations: sa = sigmoid(acc_a); sb = half0 ? tanh(acc_b) : sigmoid(acc_b)
    float ea = __expf(-acc_a);
    float sa = __builtin_amdgcn_rcpf(1.f + ea);
    float eb = __expf(sclb * acc_b);
    float tb = __builtin_amdgcn_rcpf(1.f + eb);
    float sb = fmaf(tb, mulb, addb);
    // exchange across halves: half0 sends P = sigma(i)*tanh(g); half1 sends F = sigma(f).
    float x_own = half ? sa : sa * sb;
    float x_oth = ROR16(x_own, 8);
    float so_oth = ROR16(sb, 8);       // half0 receives sigma(o)
    float P = half ? x_oth : x_own;
    float F = half ? x_own : x_oth;
    c = fmaf(F, c, P);
    float e2 = __expf(-2.f * c);
    float th = fmaf(__builtin_amdgcn_rcpf(1.f + e2), 2.f, -1.f);
    float so = half ? sb : so_oth;
    ho = so * th;                      // identical in both halves -> duplication preserved
    hsp[(size_t)s * 8] = ho;           // both halves write same value to same addr
    x0 = x1; x1 = x2;
  }
}

// ---------------- K8: dec_W1 GEMM (split-K, atomic accumulate) -------------
// grid (32 kchunks, 4 jtiles, 2 proteins), block 256
__global__ __launch_bounds__(256) void k8_dec(
    const float* __restrict__ W1, float* __restrict__ ws) {
  int ks = blockIdx.x, jt = blockIdx.y, p = blockIdx.z;
  const float* hs = ws + OFF_HS + (size_t)p * 528896;
  float* pp = ws + OFF_PPRE + (size_t)p * 16384;
  int s0 = ks * 33;
  int s1 = s0 + 33; if (s1 > Ss) s1 = Ss;
  int j0 = jt * 64;
  __shared__ __attribute__((aligned(16))) float hsl[512];
  __shared__ __attribute__((aligned(16))) float w1l[512];
  int t = threadIdx.x;
  int jl = (t & 15) * 4, bb = (t >> 4) * 4;
  f4 acc[4] = {};
  for (int s = s0; s < s1; ++s) {
    int i2 = 2 * t;
    hsl[i2]     = hs[((size_t)(i2 >> 3) * Ss + s) * 8 + (i2 & 7)];
    hsl[i2 + 1] = hs[((size_t)((i2 + 1) >> 3) * Ss + s) * 8 + ((i2 + 1) & 7)];
    w1l[t]       = W1[(size_t)(s * 8 + (t >> 6)) * 256 + j0 + (t & 63)];
    w1l[t + 256] = W1[(size_t)(s * 8 + ((t + 256) >> 6)) * 256 + j0 + ((t + 256) & 63)];
    __syncthreads();
    #pragma unroll
    for (int l = 0; l < 8; ++l) {
      f4 wv = *(const f4*)&w1l[l * 64 + jl];
      #pragma unroll
      for (int i = 0; i < 4; ++i) acc[i] += hsl[(bb + i) * 8 + l] * wv;
    }
    __syncthreads();
  }
  for (int i = 0; i < 4; ++i) {
    float* dst = pp + (size_t)(bb + i) * 256 + j0 + jl;
    atomicAdd(dst + 0, acc[i][0]); atomicAdd(dst + 1, acc[i][1]);
    atomicAdd(dst + 2, acc[i][2]); atomicAdd(dst + 3, acc[i][3]);
  }
}

// ---------------- K9: bias + relu + BatchNorm (batch stats) ----------------
// grid (2,), block 256 (thread = feature j)
__global__ __launch_bounds__(256) void k9_bn(
    const float* __restrict__ b1, const float* __restrict__ bng,
    const float* __restrict__ bnb, float* __restrict__ ws) {
  int p = blockIdx.x, j = threadIdx.x;
  const float* pp = ws + OFF_PPRE + (size_t)p * 16384;
  float* pbn = ws + OFF_PBN + (size_t)p * 16384;
  float bj = b1[j];
  float sm = 0.f, sq = 0.f;
  for (int b = 0; b < 64; ++b) {
    float v = fmaxf(pp[b * 256 + j] + bj, 0.f);
    sm += v; sq += v * v;
  }
  float m = sm * (1.f / 64.f);
  float var = fmaxf(sq * (1.f / 64.f) - m * m, 0.f);
  float rstd = rsqrtf(var + 1e-5f);
  float sc = bng[j] * rstd, sh = bnb[j] - m * sc;
  for (int b = 0; b < 64; ++b) {
    float v = fmaxf(pp[b * 256 + j] + bj, 0.f);
    pbn[b * 256 + j] = sc * v + sh;
  }
}

// ---------------- K_pre: fold small matrices through W_final ---------------
// grid (1,), block 256
__global__ __launch_bounds__(256) void k_pre(
    const float* __restrict__ W2, const float* __restrict__ b2,
    const float* __restrict__ Wm, const float* __restrict__ bm,
    const float* __restrict__ Wsd, const float* __restrict__ bsd,
    const float* __restrict__ Wf, const float* __restrict__ bf,
    float* __restrict__ ws) {
  __shared__ float wf[468];
  int t = threadIdx.x;
  for (int i = t; i < 468; i += 256) wf[i] = Wf[i];
  __syncthreads();
  float* w2f = ws + OFF_W2F;
  float* wmf = ws + OFF_WMF;
  float* wsf = ws + OFF_WSF;
  float* cst = ws + OFF_CONST;
  {
    float a1 = 0.f, a2 = 0.f;
    for (int k = 0; k < 45; ++k) {
      float v = W2[t * 45 + k];
      a1 += v * wf[128 + k];
      a2 += v * wf[346 + k];
    }
    w2f[t] = a1; w2f[256 + t] = a2;
  }
  if (t < 200) {
    float a1 = 0.f, a2 = 0.f;
    for (int k = 0; k < 45; ++k) {
      float v = Wm[t * 45 + k];
      a1 += v * wf[173 + k];
      a2 += v * wf[391 + k];
    }
    wmf[t] = a1; wmf[200 + t] = a2;
  }
  for (int i = t; i < 963; i += 256) {
    float a = 0.f;
    for (int k = 0; k < 32; ++k) a += Wsd[i * 32 + k] * wf[436 + k];
    wsf[i] = a;
  }
  if (t == 0) {
    float cc = bf[0];
    for (int k = 0; k < 45; ++k)
      cc += b2[k] * (wf[128 + k] + wf[346 + k]) + bm[k] * (wf[173 + k] + wf[391 + k]);
    for (int k = 0; k < 32; ++k) cc += bsd[k] * wf[436 + k];
    cst[0] = cc;
  }
}

// ---------------- K_final: per-row big dot ----------------------------------
// grid (64,), block 256
__global__ __launch_bounds__(256) void k_final(
    const float* __restrict__ d1m, const float* __restrict__ d2m,
    const float* __restrict__ se, const float* __restrict__ Wf,
    float* __restrict__ ws, float* __restrict__ out) {
  int b = blockIdx.x, t = threadIdx.x;
  const float* out12 = ws + OFF_OUT12;
  const float* pbn = ws + OFF_PBN;
  const float* w2f = ws + OFF_W2F;
  const float* wmf = ws + OFF_WMF;
  const float* wsf = ws + OFF_WSF;
  float acc = 0.f;
  if (t < 128) {
    acc += out12[b * 128 + t] * Wf[t];
    acc += out12[8192 + b * 128 + t] * Wf[218 + t];
  }
  acc += pbn[b * 256 + t] * w2f[t];
  acc += pbn[16384 + b * 256 + t] * w2f[256 + t];
  if (t < 200) {
    acc += d1m[b * 200 + t] * wmf[t];
    acc += d2m[b * 200 + t] * wmf[200 + t];
  }
  for (int i = t; i < 963; i += 256) acc += se[b * 963 + i] * wsf[i];
  __shared__ float red[256];
  red[t] = acc;
  __syncthreads();
  for (int off = 128; off; off >>= 1) {
    if (t < off) red[t] += red[t + off];
    __syncthreads();
  }
  if (t == 0) out[b] = red[0] + (ws + OFF_CONST)[0];
}

extern "C" void kernel_launch(void* const* d_in, const int* in_sizes, int n_in,
                              void* d_out, int out_size, void* d_ws, size_t ws_size,
                              hipStream_t stream) {
  const float* adj1  = (const float*)d_in[0];
  const float* nodes1= (const float*)d_in[1];
  const float* edges1= (const float*)d_in[2];
  const float* adj2  = (const float*)d_in[3];
  const float* nodes2= (const float*)d_in[4];
  const float* edges2= (const float*)d_in[5];
  const float* d1m   = (const float*)d_in[6];
  const float* d2m   = (const float*)d_in[7];
  const int*   ids1  = (const int*)d_in[8];
  const int*   ids2  = (const int*)d_in[9];
  const float* se    = (const float*)d_in[10];
  const float* we    = (const float*)d_in[11];
  const float* pe    = (const float*)d_in[12];
  const float* lng   = (const float*)d_in[13];
  const float* lnb   = (const float*)d_in[14];
  const float* Wih   = (const float*)d_in[15];
  const float* Whh   = (const float*)d_in[16];
  const float* bih   = (const float*)d_in[17];
  const float* bhh   = (const float*)d_in[18];
  const float* W1    = (const float*)d_in[19];
  const float* b1    = (const float*)d_in[20];
  const float* bng   = (const float*)d_in[21];
  const float* bnb   = (const float*)d_in[22];
  const float* W2    = (const float*)d_in[23];
  const float* b2    = (const float*)d_in[24];
  const float* Wm1   = (const float*)d_in[25];
  const float* We1   = (const float*)d_in[26];
  const float* Wup1  = (const float*)d_in[27];
  const float* bup1  = (const float*)d_in[28];
  const float* Wr1   = (const float*)d_in[29];
  const float* br1   = (const float*)d_in[30];
  const float* Wm2   = (const float*)d_in[31];
  const float* We2   = (const float*)d_in[32];
  const float* Wup2  = (const float*)d_in[33];
  const float* bup2  = (const float*)d_in[34];
  const float* Wr2   = (const float*)d_in[35];
  const float* br2   = (const float*)d_in[36];
  const float* Wmo   = (const float*)d_in[37];
  const float* bmo   = (const float*)d_in[38];
  const float* Wsd   = (const float*)d_in[39];
  const float* bsd   = (const float*)d_in[40];
  const float* Wf    = (const float*)d_in[41];
  const float* bf    = (const float*)d_in[42];
  float* ws = (float*)d_ws;
  float* out = (float*)d_out;

  // zero accumulators (out12 + p_pre are contiguous)
  hipMemsetAsync(ws + OFF_OUT12, 0, (2 * 8192 + 2 * 16384) * sizeof(float), stream);

  // MPNN prep: neighbor lists, edge_msg, mask, h init
  k1_prep<<<dim3(8192, 2), 64, 0, stream>>>(adj1, adj2, edges1, edges2,
                                            nodes1, nodes2, We1, We2, ws);
  // T = 3 message-passing iterations
  for (int it = 0; it < 3; ++it) {
    k_hw<<<dim3(512, 2), 256, 0, stream>>>(Wm1, Wm2, ws);
    k_msgupd<<<dim3(512, 2), 256, 0, stream>>>(Wup1, Wup2, bup1, bup2, ws);
  }
  // readout
  k_read<<<dim3(512, 2, 2), 256, 0, stream>>>(Wr1, Wr2, br1, br2, nodes1, nodes2, ws);

  // protein branch
  k6_xw<<<dim3(2066, 2), 256, 0, stream>>>(ids1, ids2, we, pe, lng, lnb, Wih, bih, bhh, ws);
  k7_lstm<<<dim3(4, 2), 256, 0, stream>>>(Whh, ws);
  k8_dec<<<dim3(32, 4, 2), 256, 0, stream>>>(W1, ws);
  k9_bn<<<2, 256, 0, stream>>>(b1, bng, bnb, ws);

  // final assembly
  k_pre<<<1, 256, 0, stream>>>(W2, b2, Wmo, bmo, Wsd, bsd, Wf, bf, ws);
  k_final<<<64, 256, 0, stream>>>(d1m, d2m, se, Wf, ws, out);
}

// Round 3
// 380.636 us; speedup vs baseline: 1.5006x; 1.4539x over previous
//
#include <hip/hip_runtime.h>
#include <hip/hip_bf16.h>
#include <math.h>

#define Bb 64
#define Nn 128
#define FNf 64
#define Ss 1033
#define EMBe 50

typedef float f4 __attribute__((ext_vector_type(4)));
typedef float f2 __attribute__((ext_vector_type(2)));

// ---- workspace offsets (in floats) ----
constexpr size_t OFF_H     = 0;                         // 2 * 524288  (h per graph)
constexpr size_t OFF_HW    = OFF_H     + 2*524288;      // 2 * 524288  (h @ W_msg)
constexpr size_t OFF_EMSG  = OFF_HW    + 2*524288;      // 2 * 524288  (edge_msg)
constexpr size_t OFF_MASK  = OFF_EMSG  + 2*524288;      // 2 * 8192    (node mask float)
constexpr size_t OFF_OUT12 = OFF_MASK  + 2*8192;        // 2 * 8192    (graph readouts)
constexpr size_t OFF_PPRE  = OFF_OUT12 + 2*8192;        // 2 * 16384   (dec1 pre-act accum)
constexpr size_t OFF_PBN   = OFF_PPRE  + 2*16384;       // 2 * 16384   (post-BN)
constexpr size_t OFF_XW    = OFF_PBN   + 2*16384;       // 2 * 2115584 (scaled x@W_ih.T + biases, permuted)
constexpr size_t OFF_HS    = OFF_XW    + 2*2115584;     // 2 * 528896  (LSTM hidden seq)
constexpr size_t OFF_W2F   = OFF_HS    + 2*528896;      // 2 * 256
constexpr size_t OFF_WMF   = OFF_W2F   + 2*256;         // 2 * 200
constexpr size_t OFF_WSF   = OFF_WMF   + 2*200;         // 963
constexpr size_t OFF_CONST = OFF_WSF   + 964;           // 4
constexpr size_t OFF_COUNT = OFF_CONST + 4;             // 2 * 8192 (int)
constexpr size_t OFF_NZ    = OFF_COUNT + 2*8192;        // 2 * 524288 (int)
constexpr size_t OFF_AVAL  = OFF_NZ    + 2*524288;      // 2 * 524288

__device__ inline f4 relu4(f4 v) {
  v[0] = fmaxf(v[0], 0.f); v[1] = fmaxf(v[1], 0.f);
  v[2] = fmaxf(v[2], 0.f); v[3] = fmaxf(v[3], 0.f);
  return v;
}

// DPP row rotate-right: dst[i] = src[(i - n) & 15] within each 16-lane row.
#define ROR16(x, n) __int_as_float(__builtin_amdgcn_update_dpp(0, __float_as_int(x), 0x120 + (n), 0xF, 0xF, true))

// ---------------- K1: adjacency compaction + edge_msg + h init -------------
// grid (8192, 2), block 64 (one wave per (b,n) row)
__global__ __launch_bounds__(64) void k1_prep(
    const float* __restrict__ adj1, const float* __restrict__ adj2,
    const float* __restrict__ edges1, const float* __restrict__ edges2,
    const float* __restrict__ nodes1, const float* __restrict__ nodes2,
    const float* __restrict__ We1, const float* __restrict__ We2,
    float* __restrict__ ws) {
  int row = blockIdx.x;
  int g = blockIdx.y;
  int t = threadIdx.x;
  const float* adj   = g ? adj2 : adj1;
  const float* edges = g ? edges2 : edges1;
  const float* nodes = g ? nodes2 : nodes1;
  const float* We    = g ? We2 : We1;
  float* h     = ws + OFF_H    + (size_t)g * 524288;
  float* emsg  = ws + OFF_EMSG + (size_t)g * 524288;
  float* maskf = ws + OFF_MASK + (size_t)g * 8192;
  int*   cntg  = (int*)(ws + OFF_COUNT) + (size_t)g * 8192;
  int*   nz    = (int*)(ws + OFF_NZ)    + (size_t)g * 524288;
  float* aval  = ws + OFF_AVAL + (size_t)g * 524288;

  __shared__ int   lidx[64];
  __shared__ float lav[64];
  __shared__ float les[16];

  const float* arow = adj + (size_t)row * 128;
  float a0 = arow[t], a1 = arow[64 + t];
  unsigned long long m0 = __ballot(a0 != 0.f);
  unsigned long long m1 = __ballot(a1 != 0.f);
  int c0 = __popcll(m0);
  int cnt = c0 + __popcll(m1);
  unsigned long long below = ((unsigned long long)1 << t) - 1ull;
  if (a0 != 0.f) { int pos = __popcll(m0 & below); if (pos < 64) { lidx[pos] = t; lav[pos] = a0; } }
  if (a1 != 0.f) { int pos = c0 + __popcll(m1 & below); if (pos < 64) { lidx[pos] = t + 64; lav[pos] = a1; } }
  int cc = cnt > 64 ? 64 : cnt;
  __syncthreads();

  // persist compact lists
  if (t < cc) { nz[(size_t)row * 64 + t] = lidx[t]; aval[(size_t)row * 64 + t] = lav[t]; }
  // init h = nodes
  h[(size_t)row * 64 + t] = nodes[(size_t)row * 64 + t];

  // es[f] = sum_nz a * edges[row, m, f]
  int f = t & 15, js = t >> 4;
  float es = 0.f;
  const float* erow = edges + (size_t)row * 128 * 16;
  for (int j = js; j < cc; j += 4) es += lav[j] * erow[lidx[j] * 16 + f];
  es += __shfl_xor(es, 16);
  es += __shfl_xor(es, 32);
  if (t < 16) les[t] = es;
  __syncthreads();

  // edge_msg[k] = sum_f es[f] * W_edge[f,k]
  float acc = 0.f;
  #pragma unroll
  for (int ff = 0; ff < 16; ++ff) acc += les[ff] * We[ff * 64 + t];
  emsg[(size_t)row * 64 + t] = acc;
  if (t == 0) { maskf[row] = cnt > 0 ? 1.f : 0.f; cntg[row] = cc; }
}

// ---------------- K_hW: hW = h @ W_msg ------------------------------------
// grid (512, 2), block 256 (16 rows per block)
__global__ __launch_bounds__(256) void k_hw(
    const float* __restrict__ Wm1, const float* __restrict__ Wm2,
    float* __restrict__ ws) {
  int g = blockIdx.y;
  const float* Wm = g ? Wm2 : Wm1;
  const float* h = ws + OFF_H + (size_t)g * 524288;
  float* hW = ws + OFF_HW + (size_t)g * 524288;
  __shared__ __attribute__((aligned(16))) float wlds[64 * 64];
  __shared__ __attribute__((aligned(16))) float hlds[16 * 64];
  int t = threadIdx.x;
  for (int i = t; i < 4096; i += 256) wlds[i] = Wm[i];
  int base = blockIdx.x * 16;
  for (int i = t; i < 1024; i += 256) hlds[i] = h[(size_t)base * 64 + i];
  __syncthreads();
  int k4 = (t & 15) * 4, rg = t >> 4;
  f4 acc = {0.f, 0.f, 0.f, 0.f};
  #pragma unroll 8
  for (int f = 0; f < 64; ++f) {
    float hv = hlds[rg * 64 + f];
    f4 w = *(const f4*)&wlds[f * 64 + k4];
    acc += hv * w;
  }
  *(f4*)&hW[(size_t)(base + rg) * 64 + k4] = acc;
}

// ---------------- K_msgupd: msg gather + update + relu + mask --------------
// grid (512, 2), block 256
__global__ __launch_bounds__(256) void k_msgupd(
    const float* __restrict__ Wup1, const float* __restrict__ Wup2,
    const float* __restrict__ bup1, const float* __restrict__ bup2,
    float* __restrict__ ws) {
  int g = blockIdx.y;
  const float* Wup = g ? Wup2 : Wup1;
  const float* bup = g ? bup2 : bup1;
  float* h = ws + OFF_H + (size_t)g * 524288;
  const float* hW = ws + OFF_HW + (size_t)g * 524288;
  const float* emsg = ws + OFF_EMSG + (size_t)g * 524288;
  const int* cntg = (const int*)(ws + OFF_COUNT) + (size_t)g * 8192;
  const int* nz = (const int*)(ws + OFF_NZ) + (size_t)g * 524288;
  const float* aval = ws + OFF_AVAL + (size_t)g * 524288;
  __shared__ __attribute__((aligned(16))) float wlds[128 * 64];
  __shared__ __attribute__((aligned(16))) float mlds[16 * 64];
  __shared__ __attribute__((aligned(16))) float hlds[16 * 64];
  int t = threadIdx.x;
  for (int i = t; i < 8192; i += 256) wlds[i] = Wup[i];
  int base = blockIdx.x * 16;
  int k4 = (t & 15) * 4, rg = t >> 4;
  int row = base + rg;
  int b = base >> 7;
  int cnt = cntg[row];
  f4 acc = *(const f4*)&emsg[(size_t)row * 64 + k4];
  const int* nzr = nz + (size_t)row * 64;
  const float* avr = aval + (size_t)row * 64;
  const float* hWb = hW + (size_t)b * 128 * 64;
  for (int j = 0; j < cnt; ++j) {
    int m = nzr[j];
    float av = avr[j];
    acc += av * *(const f4*)&hWb[m * 64 + k4];
  }
  *(f4*)&mlds[rg * 64 + k4] = acc;
  *(f4*)&hlds[rg * 64 + k4] = *(const f4*)&h[(size_t)row * 64 + k4];
  __syncthreads();
  f4 u = *(const f4*)&bup[k4];
  #pragma unroll 8
  for (int f = 0; f < 64; ++f) u += hlds[rg * 64 + f] * *(const f4*)&wlds[f * 64 + k4];
  #pragma unroll 8
  for (int f = 0; f < 64; ++f) u += mlds[rg * 64 + f] * *(const f4*)&wlds[(64 + f) * 64 + k4];
  u = relu4(u);
  if (cnt > 0) *(f4*)&h[(size_t)row * 64 + k4] = u;
}

// ---------------- K_read: readout r = relu([h,nodes]@W_read+b), masked sum -
// grid (512, 2 ktiles, 2 graphs), block 256
__global__ __launch_bounds__(256) void k_read(
    const float* __restrict__ Wr1, const float* __restrict__ Wr2,
    const float* __restrict__ br1, const float* __restrict__ br2,
    const float* __restrict__ nodes1, const float* __restrict__ nodes2,
    float* __restrict__ ws) {
  int g = blockIdx.z, kt = blockIdx.y;
  const float* Wr = g ? Wr2 : Wr1;
  const float* br = g ? br2 : br1;
  const float* nodes = g ? nodes2 : nodes1;
  const float* h = ws + OFF_H + (size_t)g * 524288;
  const float* maskf = ws + OFF_MASK + (size_t)g * 8192;
  float* out12 = ws + OFF_OUT12 + (size_t)g * 8192;
  __shared__ __attribute__((aligned(16))) float wlds[128 * 64];
  __shared__ __attribute__((aligned(16))) float hlds[16 * 64];
  __shared__ __attribute__((aligned(16))) float nlds[16 * 64];
  __shared__ __attribute__((aligned(16))) float red[16 * 64];
  int t = threadIdx.x;
  for (int i = t; i < 8192; i += 256) {
    int f = i >> 6, kk = i & 63;
    wlds[i] = Wr[f * 128 + kt * 64 + kk];
  }
  int base = blockIdx.x * 16;
  for (int i = t; i < 1024; i += 256) {
    hlds[i] = h[(size_t)base * 64 + i];
    nlds[i] = nodes[(size_t)base * 64 + i];
  }
  __syncthreads();
  int k4 = (t & 15) * 4, rg = t >> 4, row = base + rg, b = base >> 7;
  f4 acc = *(const f4*)&br[kt * 64 + k4];
  #pragma unroll 8
  for (int f = 0; f < 64; ++f) acc += hlds[rg * 64 + f] * *(const f4*)&wlds[f * 64 + k4];
  #pragma unroll 8
  for (int f = 0; f < 64; ++f) acc += nlds[rg * 64 + f] * *(const f4*)&wlds[(64 + f) * 64 + k4];
  acc = relu4(acc);
  float mf = maskf[row];
  acc *= mf;
  *(f4*)&red[rg * 64 + k4] = acc;
  __syncthreads();
  for (int off = 8; off; off >>= 1) {
    if (rg < off) {
      f4 v = *(f4*)&red[rg * 64 + k4] + *(f4*)&red[(rg + off) * 64 + k4];
      *(f4*)&red[rg * 64 + k4] = v;
    }
    __syncthreads();
  }
  if (rg == 0) {
    float* dst = out12 + (size_t)b * 128 + kt * 64 + k4;
    f4 v = *(f4*)&red[k4];
    atomicAdd(dst + 0, v[0]); atomicAdd(dst + 1, v[1]);
    atomicAdd(dst + 2, v[2]); atomicAdd(dst + 3, v[3]);
  }
}

// ---------------- K6: embedding + LayerNorm + x@W_ih.T + biases ------------
// grid (2066, 2), block 256 (8 groups x 32 lanes, 4 tokens per group)
// Output permuted for k7's 16-lane DPP scheme AND pre-scaled:
//   sigmoid gates (i,f,o) scaled by -1, tanh gate (g) scaled by -2, so k7
//   computes activations as rcp(1+exp(pre)) with no sign/scale mul on chain.
__global__ __launch_bounds__(256) void k6_xw(
    const int* __restrict__ ids1, const int* __restrict__ ids2,
    const float* __restrict__ we, const float* __restrict__ pe,
    const float* __restrict__ lng, const float* __restrict__ lnb,
    const float* __restrict__ Wih, const float* __restrict__ bih,
    const float* __restrict__ bhh, float* __restrict__ ws) {
  int p = blockIdx.y;
  const int* ids = p ? ids2 : ids1;
  float* xw = ws + OFF_XW + (size_t)p * 2115584;
  __shared__ float wlds[1600];
  __shared__ float glds[50], blds[50], bs[32];
  __shared__ float xl[8][52];
  int t = threadIdx.x;
  for (int i = t; i < 1600; i += 256) wlds[i] = Wih[i];
  if (t < 50) { glds[t] = lng[t]; blds[t] = lnb[t]; }
  if (t < 32) bs[t] = bih[t] + bhh[t];
  __syncthreads();
  int grp = t >> 5, tl = t & 31;
  int newpos = (tl < 16) ? 2 * tl : 2 * tl - 31;
  float scale = (tl >= 16 && tl < 24) ? -2.f : -1.f;
  int q0 = blockIdx.x * 32 + grp * 4;
  for (int qq = 0; qq < 4; ++qq) {
    int q = q0 + qq;                  // q = b*S + s, total exactly 64*1033
    int s = q % Ss;
    int id = ids[q];
    const float* wr = we + (size_t)id * 50;
    const float* pr = pe + (size_t)s * 50;
    float x1 = wr[tl] + pr[tl];
    bool has2 = (tl + 32) < 50;
    float x2 = has2 ? (wr[tl + 32] + pr[tl + 32]) : 0.f;
    float sm = x1 + x2, sq = x1 * x1 + x2 * x2;
    #pragma unroll
    for (int off = 16; off; off >>= 1) {
      sm += __shfl_xor(sm, off, 32);
      sq += __shfl_xor(sq, off, 32);
    }
    float u = sm * (1.f / 50.f);
    float var = fmaxf(sq * (1.f / 50.f) - u * u, 0.f);
    float rstd = rsqrtf(var + 1e-12f);
    xl[grp][tl] = glds[tl] * (x1 - u) * rstd + blds[tl];
    if (has2) xl[grp][tl + 32] = glds[tl + 32] * (x2 - u) * rstd + blds[tl + 32];
    __syncthreads();
    float acc = bs[tl];
    #pragma unroll 10
    for (int k = 0; k < 50; ++k) acc += xl[grp][k] * wlds[tl * 50 + k];
    xw[(size_t)q * 32 + newpos] = acc * scale;
    __syncthreads();
  }
}

// ---------------- K7: sequential LSTM scan (DPP + 8-deep prefetch ring) ----
// grid (32, 2), block 64: 4 batches/wave, 16 lanes per batch.
// half0 lanes k: gates (i_k, g_k); half1 lanes 8+k: gates (f_k, o_k).
// hidden ho_k duplicated at lanes k and 8+k; all cross-lane via DPP.
// cs tracks -2*c so tanh(c) = 2*rcp(1+exp(cs)) - 1 with no mul on the chain.
__global__ __launch_bounds__(64) void k7_lstm(
    const float* __restrict__ Whh, float* __restrict__ ws) {
  int p = blockIdx.y;
  const float* xw = ws + OFF_XW + (size_t)p * 2115584;
  float* hs = ws + OFF_HS + (size_t)p * 528896;
  int t = threadIdx.x;
  int lane16 = t & 15;
  int k = lane16 & 7;
  int half = lane16 >> 3;
  int b = blockIdx.x * 4 + (t >> 4);
  const float* xwp = xw + (size_t)b * Ss * 32 + lane16 * 2;
  float* hq = hs + (size_t)b * Ss * 8 + k;
  int ga = half ? 8 + k : k;          // f_k or i_k  (sigmoid, pre-scale -1)
  int gb = half ? 24 + k : 16 + k;    // o_k (sigmoid, -1) or g_k (tanh, -2)
  float sb_scale = half ? -1.f : -2.f;
  // weights pre-rotated to ROR16 delivery order and pre-scaled
  float wa[8], wb[8];
  #pragma unroll
  for (int r = 0; r < 8; ++r) {
    int j = (k - r) & 7;
    wa[r] = -Whh[ga * 8 + j];
    wb[r] = sb_scale * Whh[gb * 8 + j];
  }
  float ho = 0.f, cs = 0.f;

  f2 x[8];
  #pragma unroll
  for (int j = 0; j < 8; ++j) x[j] = *(const f2*)(xwp + (size_t)j * 32);
  const float* pf = xwp + 8 * 32;     // prefetch pointer (step s+8)

  auto step = [&](f2 xc) {
    float acc_a = fmaf(ho, wa[0], xc.x);
    float acc_b = fmaf(ho, wb[0], xc.y);
    float h1 = ROR16(ho, 1); acc_a = fmaf(h1, wa[1], acc_a); acc_b = fmaf(h1, wb[1], acc_b);
    float h2 = ROR16(ho, 2); acc_a = fmaf(h2, wa[2], acc_a); acc_b = fmaf(h2, wb[2], acc_b);
    float h3 = ROR16(ho, 3); acc_a = fmaf(h3, wa[3], acc_a); acc_b = fmaf(h3, wb[3], acc_b);
    float h4 = ROR16(ho, 4); acc_a = fmaf(h4, wa[4], acc_a); acc_b = fmaf(h4, wb[4], acc_b);
    float h5 = ROR16(ho, 5); acc_a = fmaf(h5, wa[5], acc_a); acc_b = fmaf(h5, wb[5], acc_b);
    float h6 = ROR16(ho, 6); acc_a = fmaf(h6, wa[6], acc_a); acc_b = fmaf(h6, wb[6], acc_b);
    float h7 = ROR16(ho, 7); acc_a = fmaf(h7, wa[7], acc_a); acc_b = fmaf(h7, wb[7], acc_b);
    // sa = sigmoid(i or f); tb = sigmoid(o) [half1] or (tanh(g)+1)/2 [half0]
    float ea = __expf(acc_a);
    float sa = __builtin_amdgcn_rcpf(1.f + ea);
    float eb = __expf(acc_b);
    float tb = __builtin_amdgcn_rcpf(1.f + eb);
    float m4sa = -4.f * sa, p2sa = sa + sa;       // off-chain (sa ready early)
    float x_own = half ? sa : fmaf(m4sa, tb, p2sa);   // half0: -2*i*g; half1: f
    float x_oth = ROR16(x_own, 8);
    float t_oth = ROR16(tb, 8);
    float F  = half ? x_own : x_oth;
    float P2 = half ? x_oth : x_own;
    cs = fmaf(F, cs, P2);                          // cs = -2*c
    float e2 = __expf(cs);
    float tc = __builtin_amdgcn_rcpf(1.f + e2);
    float so = half ? tb : t_oth;                  // sigma(o), both halves
    float so2 = so + so, nso = -so;                // off-chain
    ho = fmaf(so2, tc, nso);                       // so * tanh(c)
    if (!half) *hq = ho;
    hq += 8;
  };

  for (int it = 0; it < 129; ++it) {               // 129*8 = 1032 steps
    #pragma unroll
    for (int j = 0; j < 8; ++j) {
      f2 xc = x[j];
      x[j] = *(const f2*)pf;                       // prefetch step s+8 into freed slot
      pf += 32;                                    // (overruns into OFF_HS region; never consumed)
      step(xc);
    }
  }
  step(x[0]);                                      // final step 1032
}

// ---------------- K8: dec_W1 GEMM (split-K, atomic accumulate) -------------
// grid (32 kchunks, 4 jtiles, 2 proteins), block 256
__global__ __launch_bounds__(256) void k8_dec(
    const float* __restrict__ W1, float* __restrict__ ws) {
  int ks = blockIdx.x, jt = blockIdx.y, p = blockIdx.z;
  const float* hs = ws + OFF_HS + (size_t)p * 528896;
  float* pp = ws + OFF_PPRE + (size_t)p * 16384;
  int s0 = ks * 33;
  int s1 = s0 + 33; if (s1 > Ss) s1 = Ss;
  int j0 = jt * 64;
  __shared__ __attribute__((aligned(16))) float hsl[512];
  __shared__ __attribute__((aligned(16))) float w1l[512];
  int t = threadIdx.x;
  int jl = (t & 15) * 4, bb = (t >> 4) * 4;
  f4 acc[4] = {};
  for (int s = s0; s < s1; ++s) {
    int i2 = 2 * t;
    hsl[i2]     = hs[((size_t)(i2 >> 3) * Ss + s) * 8 + (i2 & 7)];
    hsl[i2 + 1] = hs[((size_t)((i2 + 1) >> 3) * Ss + s) * 8 + ((i2 + 1) & 7)];
    w1l[t]       = W1[(size_t)(s * 8 + (t >> 6)) * 256 + j0 + (t & 63)];
    w1l[t + 256] = W1[(size_t)(s * 8 + ((t + 256) >> 6)) * 256 + j0 + ((t + 256) & 63)];
    __syncthreads();
    #pragma unroll
    for (int l = 0; l < 8; ++l) {
      f4 wv = *(const f4*)&w1l[l * 64 + jl];
      #pragma unroll
      for (int i = 0; i < 4; ++i) acc[i] += hsl[(bb + i) * 8 + l] * wv;
    }
    __syncthreads();
  }
  for (int i = 0; i < 4; ++i) {
    float* dst = pp + (size_t)(bb + i) * 256 + j0 + jl;
    atomicAdd(dst + 0, acc[i][0]); atomicAdd(dst + 1, acc[i][1]);
    atomicAdd(dst + 2, acc[i][2]); atomicAdd(dst + 3, acc[i][3]);
  }
}

// ---------------- K9: bias + relu + BatchNorm (batch stats) ----------------
// grid (2,), block 256 (thread = feature j)
__global__ __launch_bounds__(256) void k9_bn(
    const float* __restrict__ b1, const float* __restrict__ bng,
    const float* __restrict__ bnb, float* __restrict__ ws) {
  int p = blockIdx.x, j = threadIdx.x;
  const float* pp = ws + OFF_PPRE + (size_t)p * 16384;
  float* pbn = ws + OFF_PBN + (size_t)p * 16384;
  float bj = b1[j];
  float sm = 0.f, sq = 0.f;
  for (int b = 0; b < 64; ++b) {
    float v = fmaxf(pp[b * 256 + j] + bj, 0.f);
    sm += v; sq += v * v;
  }
  float m = sm * (1.f / 64.f);
  float var = fmaxf(sq * (1.f / 64.f) - m * m, 0.f);
  float rstd = rsqrtf(var + 1e-5f);
  float sc = bng[j] * rstd, sh = bnb[j] - m * sc;
  for (int b = 0; b < 64; ++b) {
    float v = fmaxf(pp[b * 256 + j] + bj, 0.f);
    pbn[b * 256 + j] = sc * v + sh;
  }
}

// ---------------- K_pre: fold small matrices through W_final ---------------
// grid (1,), block 256
__global__ __launch_bounds__(256) void k_pre(
    const float* __restrict__ W2, const float* __restrict__ b2,
    const float* __restrict__ Wm, const float* __restrict__ bm,
    const float* __restrict__ Wsd, const float* __restrict__ bsd,
    const float* __restrict__ Wf, const float* __restrict__ bf,
    float* __restrict__ ws) {
  __shared__ float wf[468];
  int t = threadIdx.x;
  for (int i = t; i < 468; i += 256) wf[i] = Wf[i];
  __syncthreads();
  float* w2f = ws + OFF_W2F;
  float* wmf = ws + OFF_WMF;
  float* wsf = ws + OFF_WSF;
  float* cst = ws + OFF_CONST;
  {
    float a1 = 0.f, a2 = 0.f;
    for (int k = 0; k < 45; ++k) {
      float v = W2[t * 45 + k];
      a1 += v * wf[128 + k];
      a2 += v * wf[346 + k];
    }
    w2f[t] = a1; w2f[256 + t] = a2;
  }
  if (t < 200) {
    float a1 = 0.f, a2 = 0.f;
    for (int k = 0; k < 45; ++k) {
      float v = Wm[t * 45 + k];
      a1 += v * wf[173 + k];
      a2 += v * wf[391 + k];
    }
    wmf[t] = a1; wmf[200 + t] = a2;
  }
  for (int i = t; i < 963; i += 256) {
    float a = 0.f;
    for (int k = 0; k < 32; ++k) a += Wsd[i * 32 + k] * wf[436 + k];
    wsf[i] = a;
  }
  if (t == 0) {
    float cc = bf[0];
    for (int k = 0; k < 45; ++k)
      cc += b2[k] * (wf[128 + k] + wf[346 + k]) + bm[k] * (wf[173 + k] + wf[391 + k]);
    for (int k = 0; k < 32; ++k) cc += bsd[k] * wf[436 + k];
    cst[0] = cc;
  }
}

// ---------------- K_final: per-row big dot ----------------------------------
// grid (64,), block 256
__global__ __launch_bounds__(256) void k_final(
    const float* __restrict__ d1m, const float* __restrict__ d2m,
    const float* __restrict__ se, const float* __restrict__ Wf,
    float* __restrict__ ws, float* __restrict__ out) {
  int b = blockIdx.x, t = threadIdx.x;
  const float* out12 = ws + OFF_OUT12;
  const float* pbn = ws + OFF_PBN;
  const float* w2f = ws + OFF_W2F;
  const float* wmf = ws + OFF_WMF;
  const float* wsf = ws + OFF_WSF;
  float acc = 0.f;
  if (t < 128) {
    acc += out12[b * 128 + t] * Wf[t];
    acc += out12[8192 + b * 128 + t] * Wf[218 + t];
  }
  acc += pbn[b * 256 + t] * w2f[t];
  acc += pbn[16384 + b * 256 + t] * w2f[256 + t];
  if (t < 200) {
    acc += d1m[b * 200 + t] * wmf[t];
    acc += d2m[b * 200 + t] * wmf[200 + t];
  }
  for (int i = t; i < 963; i += 256) acc += se[b * 963 + i] * wsf[i];
  __shared__ float red[256];
  red[t] = acc;
  __syncthreads();
  for (int off = 128; off; off >>= 1) {
    if (t < off) red[t] += red[t + off];
    __syncthreads();
  }
  if (t == 0) out[b] = red[0] + (ws + OFF_CONST)[0];
}

extern "C" void kernel_launch(void* const* d_in, const int* in_sizes, int n_in,
                              void* d_out, int out_size, void* d_ws, size_t ws_size,
                              hipStream_t stream) {
  const float* adj1  = (const float*)d_in[0];
  const float* nodes1= (const float*)d_in[1];
  const float* edges1= (const float*)d_in[2];
  const float* adj2  = (const float*)d_in[3];
  const float* nodes2= (const float*)d_in[4];
  const float* edges2= (const float*)d_in[5];
  const float* d1m   = (const float*)d_in[6];
  const float* d2m   = (const float*)d_in[7];
  const int*   ids1  = (const int*)d_in[8];
  const int*   ids2  = (const int*)d_in[9];
  const float* se    = (const float*)d_in[10];
  const float* we    = (const float*)d_in[11];
  const float* pe    = (const float*)d_in[12];
  const float* lng   = (const float*)d_in[13];
  const float* lnb   = (const float*)d_in[14];
  const float* Wih   = (const float*)d_in[15];
  const float* Whh   = (const float*)d_in[16];
  const float* bih   = (const float*)d_in[17];
  const float* bhh   = (const float*)d_in[18];
  const float* W1    = (const float*)d_in[19];
  const float* b1    = (const float*)d_in[20];
  const float* bng   = (const float*)d_in[21];
  const float* bnb   = (const float*)d_in[22];
  const float* W2    = (const float*)d_in[23];
  const float* b2    = (const float*)d_in[24];
  const float* Wm1   = (const float*)d_in[25];
  const float* We1   = (const float*)d_in[26];
  const float* Wup1  = (const float*)d_in[27];
  const float* bup1  = (const float*)d_in[28];
  const float* Wr1   = (const float*)d_in[29];
  const float* br1   = (const float*)d_in[30];
  const float* Wm2   = (const float*)d_in[31];
  const float* We2   = (const float*)d_in[32];
  const float* Wup2  = (const float*)d_in[33];
  const float* bup2  = (const float*)d_in[34];
  const float* Wr2   = (const float*)d_in[35];
  const float* br2   = (const float*)d_in[36];
  const float* Wmo   = (const float*)d_in[37];
  const float* bmo   = (const float*)d_in[38];
  const float* Wsd   = (const float*)d_in[39];
  const float* bsd   = (const float*)d_in[40];
  const float* Wf    = (const float*)d_in[41];
  const float* bf    = (const float*)d_in[42];
  float* ws = (float*)d_ws;
  float* out = (float*)d_out;

  // zero accumulators (out12 + p_pre are contiguous)
  hipMemsetAsync(ws + OFF_OUT12, 0, (2 * 8192 + 2 * 16384) * sizeof(float), stream);

  // MPNN prep: neighbor lists, edge_msg, mask, h init
  k1_prep<<<dim3(8192, 2), 64, 0, stream>>>(adj1, adj2, edges1, edges2,
                                            nodes1, nodes2, We1, We2, ws);
  // T = 3 message-passing iterations
  for (int it = 0; it < 3; ++it) {
    k_hw<<<dim3(512, 2), 256, 0, stream>>>(Wm1, Wm2, ws);
    k_msgupd<<<dim3(512, 2), 256, 0, stream>>>(Wup1, Wup2, bup1, bup2, ws);
  }
  // readout
  k_read<<<dim3(512, 2, 2), 256, 0, stream>>>(Wr1, Wr2, br1, br2, nodes1, nodes2, ws);

  // protein branch
  k6_xw<<<dim3(2066, 2), 256, 0, stream>>>(ids1, ids2, we, pe, lng, lnb, Wih, bih, bhh, ws);
  k7_lstm<<<dim3(32, 2), 64, 0, stream>>>(Whh, ws);
  k8_dec<<<dim3(32, 4, 2), 256, 0, stream>>>(W1, ws);
  k9_bn<<<2, 256, 0, stream>>>(b1, bng, bnb, ws);

  // final assembly
  k_pre<<<1, 256, 0, stream>>>(W2, b2, Wmo, bmo, Wsd, bsd, Wf, bf, ws);
  k_final<<<64, 256, 0, stream>>>(d1m, d2m, se, Wf, ws, out);
}